// Round 1
// baseline (107.759 us; speedup 1.0000x reference)
//
#include <hip/hip_runtime.h>
#include <math.h>

#define B  4
#define NF 4096
#define FM 32
#define H  128
#define NC 256
#define ROW (FM * H)   // 4096 floats per (b,n) row

// ---------------- Kernel 1: scores[b*NF+n] = dot(mean_f x, W) + b0 ----------
// One wave (64 lanes) per row. Row = 4096 floats = 1024 float4.
// lane handles float4 indices lane + j*64 (j=0..15); element e = 4*lane+256*j,
// h = e mod 128 = 4*(lane&31)  -> W fragment is lane-constant.
__global__ __launch_bounds__(256) void k_scores(const float* __restrict__ x,
                                                const float* __restrict__ W,
                                                const float* __restrict__ bias,
                                                float* __restrict__ scores) {
    const int wid  = threadIdx.x >> 6;
    const int lane = threadIdx.x & 63;
    const int row  = blockIdx.x * 4 + wid;          // 0 .. B*NF-1
    const float4* rp = (const float4*)(x + (size_t)row * ROW);
    const float4  w4 = ((const float4*)W)[lane & 31];

    float acc = 0.f;
#pragma unroll
    for (int j = 0; j < 16; ++j) {
        float4 v = rp[lane + j * 64];
        acc += v.x * w4.x + v.y * w4.y + v.z * w4.z + v.w * w4.w;
    }
#pragma unroll
    for (int off = 32; off >= 1; off >>= 1)
        acc += __shfl_xor(acc, off, 64);

    if (lane == 0)
        scores[row] = acc * (1.0f / FM) + bias[0];
}

// ---------------- Kernel 2: segmented softmax weights ----------------------
__device__ inline unsigned enc_f(float f) {
    unsigned b = __float_as_uint(f);
    return (b & 0x80000000u) ? ~b : (b | 0x80000000u);
}
__device__ inline float dec_f(unsigned u) {
    return __uint_as_float((u & 0x80000000u) ? (u & 0x7fffffffu) : ~u);
}

__global__ __launch_bounds__(256) void k_softmax(const float* __restrict__ scores,
                                                 const int* __restrict__ seg,
                                                 float* __restrict__ w) {
    __shared__ unsigned smax[NC];
    __shared__ float    denom[NC];
    const int b = blockIdx.x;
    const int t = threadIdx.x;

    smax[t]  = enc_f(-INFINITY);
    denom[t] = 0.f;
    __syncthreads();

    float s[NF / 256];
    int   sg[NF / 256];
#pragma unroll
    for (int i = 0; i < NF / 256; ++i) {
        const int n = t + i * 256;
        s[i]  = scores[b * NF + n];
        sg[i] = seg[n];
        atomicMax(&smax[sg[i]], enc_f(s[i]));
    }
    __syncthreads();

    float e[NF / 256];
#pragma unroll
    for (int i = 0; i < NF / 256; ++i) {
        e[i] = expf(s[i] - dec_f(smax[sg[i]]));
        atomicAdd(&denom[sg[i]], e[i]);
    }
    __syncthreads();

#pragma unroll
    for (int i = 0; i < NF / 256; ++i) {
        const int n = t + i * 256;
        w[b * NF + n] = e[i] / denom[sg[i]];
    }
}

// ---------------- Kernel 3: gather-reduce out[b,c] = sum_{n in c} w_n * x_n -
// One block per (b,c). Member list built in LDS, then register accumulation:
// each thread owns 4 float4 (16 floats) of the 4096-float row. No atomics to
// global memory; every x row is read exactly once across the whole grid.
__global__ __launch_bounds__(256) void k_scatter(const float* __restrict__ x,
                                                 const float* __restrict__ w,
                                                 const int* __restrict__ seg,
                                                 float* __restrict__ out) {
    __shared__ int members[NF];
    __shared__ int cnt;
    const int b = blockIdx.x >> 8;        // / NC
    const int c = blockIdx.x & (NC - 1);  // % NC
    const int t = threadIdx.x;

    if (t == 0) cnt = 0;
    __syncthreads();

#pragma unroll
    for (int i = 0; i < NF / 256; ++i) {
        const int n = t + i * 256;
        if (seg[n] == c) {
            int p = atomicAdd(&cnt, 1);
            members[p] = n;
        }
    }
    __syncthreads();

    const int m = cnt;
    float4 acc[4];
#pragma unroll
    for (int j = 0; j < 4; ++j) acc[j] = make_float4(0.f, 0.f, 0.f, 0.f);

    for (int k = 0; k < m; ++k) {
        const int   n  = members[k];
        const float wv = w[b * NF + n];
        const float4* rp = (const float4*)(x + (size_t)(b * NF + n) * ROW);
#pragma unroll
        for (int j = 0; j < 4; ++j) {
            float4 v = rp[t + j * 256];
            acc[j].x += wv * v.x;
            acc[j].y += wv * v.y;
            acc[j].z += wv * v.z;
            acc[j].w += wv * v.w;
        }
    }

    float4* op = (float4*)(out + (size_t)(b * NC + c) * ROW);
#pragma unroll
    for (int j = 0; j < 4; ++j)
        op[t + j * 256] = acc[j];
}

// ---------------------------------------------------------------------------
extern "C" void kernel_launch(void* const* d_in, const int* in_sizes, int n_in,
                              void* d_out, int out_size, void* d_ws, size_t ws_size,
                              hipStream_t stream) {
    const float* x    = (const float*)d_in[0];
    const float* W    = (const float*)d_in[1];
    const float* bias = (const float*)d_in[2];
    const int*   seg  = (const int*)d_in[3];
    float*       out  = (float*)d_out;

    float* scores = (float*)d_ws;            // B*NF floats
    float* w      = scores + B * NF;         // B*NF floats

    k_scores <<<B * NF / 4, 256, 0, stream>>>(x, W, bias, scores);
    k_softmax<<<B,          256, 0, stream>>>(scores, seg, w);
    k_scatter<<<B * NC,     256, 0, stream>>>(x, w, seg, out);
}

// Round 2
// 91.430 us; speedup vs baseline: 1.1786x; 1.1786x over previous
//
#include <hip/hip_runtime.h>
#include <math.h>

#define B   4
#define NF  4096
#define FM  32
#define H   128
#define NC  256
#define ROW (FM * H)      // 4096 floats per (b,n) row
#define CH  4             // chunks per row in the gather kernel
#define CHF (ROW / CH)    // 1024 floats per chunk = 256 float4
#define TILE 512          // member tile cached in LDS

// ---------------- Kernel A ---------------------------------------------------
// Blocks 0..4095: scores[b*NF+n] = dot(mean_f x, W) + b0   (one wave per row)
// Block 4096:     build CSR of segment_ids -> offs[NC+1], perm[NF]
__global__ __launch_bounds__(256) void k_scores_csr(const float* __restrict__ x,
                                                    const float* __restrict__ W,
                                                    const float* __restrict__ bias,
                                                    const int* __restrict__ seg,
                                                    float* __restrict__ scores,
                                                    int* __restrict__ offs,
                                                    int* __restrict__ perm) {
    const int t = threadIdx.x;

    if (blockIdx.x < B * NF / 4) {
        // ---- scores path: 4 waves/block, one row per wave ----
        const int wid  = t >> 6;
        const int lane = t & 63;
        const int row  = blockIdx.x * 4 + wid;
        const float4* rp = (const float4*)(x + (size_t)row * ROW);
        const float4  w4 = ((const float4*)W)[lane & 31];

        float acc = 0.f;
#pragma unroll
        for (int j = 0; j < 16; ++j) {
            float4 v = rp[lane + j * 64];
            acc += v.x * w4.x + v.y * w4.y + v.z * w4.z + v.w * w4.w;
        }
#pragma unroll
        for (int off = 32; off >= 1; off >>= 1)
            acc += __shfl_xor(acc, off, 64);
        if (lane == 0)
            scores[row] = acc * (1.0f / FM) + bias[0];
    } else {
        // ---- CSR path: one block, 256 threads ----
        __shared__ int cnt[NC];
        __shared__ int sc[NC];
        __shared__ int cursor[NC];

        cnt[t] = 0;
        __syncthreads();
#pragma unroll
        for (int i = 0; i < NF / 256; ++i)
            atomicAdd(&cnt[seg[t + i * 256]], 1);
        __syncthreads();

        // inclusive Hillis-Steele scan over 256 counts
        sc[t] = cnt[t];
        __syncthreads();
        for (int d = 1; d < NC; d <<= 1) {
            int v = (t >= d) ? sc[t - d] : 0;
            __syncthreads();
            sc[t] += v;
            __syncthreads();
        }
        const int ex = sc[t] - cnt[t];   // exclusive prefix
        offs[t]   = ex;
        cursor[t] = ex;
        if (t == 0) offs[NC] = NF;
        __syncthreads();

#pragma unroll
        for (int i = 0; i < NF / 256; ++i) {
            const int n = t + i * 256;
            const int p = atomicAdd(&cursor[seg[n]], 1);
            perm[p] = n;
        }
    }
}

// ---------------- Kernel B ---------------------------------------------------
// One block per (b, c, chunk). Computes the segment softmax stats itself
// (scores is 64 KB, L2-resident), then gathers w_n * x_n over the chunk's
// 1024 floats. No global atomics; each x element read exactly once per chunk.
__global__ __launch_bounds__(256) void k_pool(const float* __restrict__ x,
                                              const float* __restrict__ scores,
                                              const int* __restrict__ offs,
                                              const int* __restrict__ perm,
                                              float* __restrict__ out) {
    __shared__ float red[256];
    __shared__ int   sm_row[TILE];
    __shared__ float sm_w[TILE];

    const int t     = threadIdx.x;
    const int bid   = blockIdx.x;
    const int chunk = bid & (CH - 1);
    const int c     = (bid >> 2) & (NC - 1);
    const int b     = bid >> 10;

    const int off0 = offs[c];
    const int m    = offs[c + 1] - off0;
    const float* sb = scores + b * NF;

    // ---- segment max ----
    float pm = -INFINITY;
    for (int k = t; k < m; k += 256)
        pm = fmaxf(pm, sb[perm[off0 + k]]);
    red[t] = pm;
    __syncthreads();
    for (int s = 128; s > 0; s >>= 1) {
        if (t < s) red[t] = fmaxf(red[t], red[t + s]);
        __syncthreads();
    }
    const float smax = red[0];
    __syncthreads();

    // ---- segment denom ----
    float ps = 0.f;
    for (int k = t; k < m; k += 256)
        ps += expf(sb[perm[off0 + k]] - smax);
    red[t] = ps;
    __syncthreads();
    for (int s = 128; s > 0; s >>= 1) {
        if (t < s) red[t] += red[t + s];
        __syncthreads();
    }
    const float rden = 1.0f / red[0];
    __syncthreads();

    // ---- weighted gather over this chunk ----
    float4 acc = make_float4(0.f, 0.f, 0.f, 0.f);
    const size_t choff = (size_t)chunk * CHF;

    for (int base = 0; base < m; base += TILE) {
        const int mt = min(TILE, m - base);
        if (t < mt) {
            const int r = perm[off0 + base + t];
            sm_row[t] = r;
            sm_w[t]   = expf(sb[r] - smax) * rden;
        }
        __syncthreads();
        for (int k = 0; k < mt; ++k) {
            const float wv = sm_w[k];
            const float4* rp = (const float4*)(x + (size_t)(b * NF + sm_row[k]) * ROW + choff);
            float4 v = rp[t];
            acc.x += wv * v.x;
            acc.y += wv * v.y;
            acc.z += wv * v.z;
            acc.w += wv * v.w;
        }
        __syncthreads();
    }

    float4* op = (float4*)(out + (size_t)(b * NC + c) * ROW + choff);
    op[t] = acc;
}

// ---------------------------------------------------------------------------
extern "C" void kernel_launch(void* const* d_in, const int* in_sizes, int n_in,
                              void* d_out, int out_size, void* d_ws, size_t ws_size,
                              hipStream_t stream) {
    const float* x    = (const float*)d_in[0];
    const float* W    = (const float*)d_in[1];
    const float* bias = (const float*)d_in[2];
    const int*   seg  = (const int*)d_in[3];
    float*       out  = (float*)d_out;

    float* scores = (float*)d_ws;              // B*NF floats
    int*   offs   = (int*)(scores + B * NF);   // NC+1 ints
    int*   perm   = offs + (NC + 1);           // NF ints

    k_scores_csr<<<B * NF / 4 + 1, 256, 0, stream>>>(x, W, bias, seg, scores, offs, perm);
    k_pool      <<<B * NC * CH,    256, 0, stream>>>(x, scores, offs, perm, out);
}

// Round 3
// 89.932 us; speedup vs baseline: 1.1982x; 1.0167x over previous
//
#include <hip/hip_runtime.h>
#include <math.h>

#define B   4
#define NF  4096
#define FM  32
#define H   128
#define NC  256
#define ROW (FM * H)      // 4096 floats per (b,n) row
#define CH  4             // chunks per row in the gather kernel
#define CHF (ROW / CH)    // 1024 floats per chunk = 256 float4
#define TILE 512          // member tile cached in LDS

// ---------------- Kernel A ---------------------------------------------------
// Blocks 0..4095: scores[b*NF+n] = dot(mean_f x, W) + b0   (one wave per row)
// Block 4096:     build CSR of segment_ids -> offs[NC+1], perm[NF]
__global__ __launch_bounds__(256) void k_scores_csr(const float* __restrict__ x,
                                                    const float* __restrict__ W,
                                                    const float* __restrict__ bias,
                                                    const int* __restrict__ seg,
                                                    float* __restrict__ scores,
                                                    int* __restrict__ offs,
                                                    int* __restrict__ perm) {
    const int t = threadIdx.x;

    if (blockIdx.x < B * NF / 4) {
        // ---- scores path: 4 waves/block, one row per wave ----
        const int wid  = t >> 6;
        const int lane = t & 63;
        const int row  = blockIdx.x * 4 + wid;
        const float4* rp = (const float4*)(x + (size_t)row * ROW);
        const float4  w4 = ((const float4*)W)[lane & 31];

        float acc = 0.f;
#pragma unroll
        for (int j = 0; j < 16; ++j) {
            float4 v = rp[lane + j * 64];
            acc += v.x * w4.x + v.y * w4.y + v.z * w4.z + v.w * w4.w;
        }
#pragma unroll
        for (int off = 32; off >= 1; off >>= 1)
            acc += __shfl_xor(acc, off, 64);
        if (lane == 0)
            scores[row] = acc * (1.0f / FM) + bias[0];
    } else {
        // ---- CSR path: one block, 256 threads ----
        __shared__ int cnt[NC];
        __shared__ int sc[NC];
        __shared__ int cursor[NC];

        cnt[t] = 0;
        __syncthreads();
#pragma unroll
        for (int i = 0; i < NF / 256; ++i)
            atomicAdd(&cnt[seg[t + i * 256]], 1);
        __syncthreads();

        // inclusive Hillis-Steele scan over 256 counts
        sc[t] = cnt[t];
        __syncthreads();
        for (int d = 1; d < NC; d <<= 1) {
            int v = (t >= d) ? sc[t - d] : 0;
            __syncthreads();
            sc[t] += v;
            __syncthreads();
        }
        const int ex = sc[t] - cnt[t];   // exclusive prefix
        offs[t]   = ex;
        cursor[t] = ex;
        if (t == 0) offs[NC] = NF;
        __syncthreads();

#pragma unroll
        for (int i = 0; i < NF / 256; ++i) {
            const int n = t + i * 256;
            const int p = atomicAdd(&cursor[seg[n]], 1);
            perm[p] = n;
        }
    }
}

// ---------------- Kernel B ---------------------------------------------------
// One block per (b, c, chunk). Every wave redundantly computes the segment
// softmax stats with shuffle reductions (scores are L2/L3-resident, m ~ 16,
// so this is ~1 strided iteration, no extra barriers). Then a weighted
// gather over the chunk's 1024 floats; each x element read exactly once.
__global__ __launch_bounds__(256) void k_pool(const float* __restrict__ x,
                                              const float* __restrict__ scores,
                                              const int* __restrict__ offs,
                                              const int* __restrict__ perm,
                                              float* __restrict__ out) {
    __shared__ int   sm_row[TILE];
    __shared__ float sm_w[TILE];

    const int t     = threadIdx.x;
    const int lane  = t & 63;
    const int bid   = blockIdx.x;
    const int chunk = bid & (CH - 1);
    const int c     = (bid >> 2) & (NC - 1);
    const int b     = bid >> 10;

    const int off0 = offs[c];
    const int m    = offs[c + 1] - off0;
    const float* sb = scores + b * NF;

    // ---- per-wave redundant segment stats (no barriers) ----
    float pm = -INFINITY;
    for (int k = lane; k < m; k += 64)
        pm = fmaxf(pm, sb[perm[off0 + k]]);
#pragma unroll
    for (int off = 32; off >= 1; off >>= 1)
        pm = fmaxf(pm, __shfl_xor(pm, off, 64));
    const float smax = pm;

    float ps = 0.f;
    for (int k = lane; k < m; k += 64)
        ps += expf(sb[perm[off0 + k]] - smax);
#pragma unroll
    for (int off = 32; off >= 1; off >>= 1)
        ps += __shfl_xor(ps, off, 64);
    const float rden = 1.0f / ps;

    // ---- weighted gather over this chunk ----
    float4 acc0 = make_float4(0.f, 0.f, 0.f, 0.f);
    float4 acc1 = make_float4(0.f, 0.f, 0.f, 0.f);
    const float4* xb = (const float4*)x + (size_t)b * NF * (ROW / 4)
                     + (size_t)chunk * (CHF / 4) + t;

    for (int base = 0; base < m; base += TILE) {
        const int mt = min(TILE, m - base);
        __syncthreads();                       // protect LDS reuse across tiles
        if (t < mt) {
            const int r = perm[off0 + base + t];
            sm_row[t] = r;
            sm_w[t]   = expf(sb[r] - smax) * rden;
        }
        __syncthreads();

        int k = 0;
        for (; k + 2 <= mt; k += 2) {
            const float w0 = sm_w[k];
            const float w1 = sm_w[k + 1];
            const float4 v0 = xb[(size_t)sm_row[k]     * (ROW / 4)];
            const float4 v1 = xb[(size_t)sm_row[k + 1] * (ROW / 4)];
            acc0.x += w0 * v0.x; acc0.y += w0 * v0.y;
            acc0.z += w0 * v0.z; acc0.w += w0 * v0.w;
            acc1.x += w1 * v1.x; acc1.y += w1 * v1.y;
            acc1.z += w1 * v1.z; acc1.w += w1 * v1.w;
        }
        if (k < mt) {
            const float w0 = sm_w[k];
            const float4 v0 = xb[(size_t)sm_row[k] * (ROW / 4)];
            acc0.x += w0 * v0.x; acc0.y += w0 * v0.y;
            acc0.z += w0 * v0.z; acc0.w += w0 * v0.w;
        }
    }

    acc0.x += acc1.x; acc0.y += acc1.y; acc0.z += acc1.z; acc0.w += acc1.w;
    float4* op = (float4*)(out + (size_t)(b * NC + c) * ROW + (size_t)chunk * CHF);
    op[t] = acc0;
}

// ---------------------------------------------------------------------------
extern "C" void kernel_launch(void* const* d_in, const int* in_sizes, int n_in,
                              void* d_out, int out_size, void* d_ws, size_t ws_size,
                              hipStream_t stream) {
    const float* x    = (const float*)d_in[0];
    const float* W    = (const float*)d_in[1];
    const float* bias = (const float*)d_in[2];
    const int*   seg  = (const int*)d_in[3];
    float*       out  = (float*)d_out;

    float* scores = (float*)d_ws;              // B*NF floats
    int*   offs   = (int*)(scores + B * NF);   // NC+1 ints
    int*   perm   = offs + (NC + 1);           // NF ints

    k_scores_csr<<<B * NF / 4 + 1, 256, 0, stream>>>(x, W, bias, seg, scores, offs, perm);
    k_pool      <<<B * NC * CH,    256, 0, stream>>>(x, scores, offs, perm, out);
}